// Round 11
// baseline (125.094 us; speedup 1.0000x reference)
//
#include <hip/hip_runtime.h>

// ChamferLoss: x,y (16,4096,3) f32 -> scalar.
// R11: fixes R10's coverage bug (db was split across td AND tq but reduced
// only across td -> each query saw 128/1024 of the wave's points). Now:
// ONE query per wave-step broadcast to all 64 lanes (uniform ds_read_b128),
// each lane holds 16 db pts f2-packed in VGPRs (24 v_pk_fma_f32 + 8 v_min3
// per 1024 pair-evals), full 6-step shfl_xor wave reduction -> every wave
// point vs every query by construction. 4 waves/block cover the 4096-pt db;
// per-query combine via 2KB qpart. Inner loop has ZERO LDS reads (R9 showed
// LDS/VALU parity was the R8 ceiling). 1024 blocks x 4 waves, 4 blocks/CU.

#define NP 4096
#define NB 16
#define BLK 256
#define NZZ (2 * NB)            // 32 (dir,b)
#define QPB 128                 // queries per block
#define BPZ (NP / QPB)          // 32 blocks per zz
#define NBLOCKS (NZZ * BPZ)     // 1024
#define PPL 16                  // db points per lane
#define PPW (64 * PPL)          // 1024 db points per wave

typedef float f2 __attribute__((ext_vector_type(2)));

__global__ void chamfer_init(float* __restrict__ out) { out[0] = 0.0f; }

__global__ __launch_bounds__(BLK, 4) void chamfer_main(
    const float* __restrict__ x, const float* __restrict__ y,
    float* __restrict__ out) {
  const int bid  = blockIdx.x;
  const int zz   = bid >> 5;          // /BPZ
  const int qblk = bid & (BPZ - 1);
  const int dir  = zz >> 4;
  const int b    = zz & 15;

  const float* q_base = (dir == 0 ? x : y) + (size_t)b * NP * 3;
  const float* d_base = (dir == 0 ? y : x) + (size_t)b * NP * 3;

  __shared__ float4 qds[QPB];         // (-2qx,-2qy,-2qz,q2)  2 KB
  __shared__ float  qpart[QPB * 4];   // per-wave partial mins 2 KB
  __shared__ float  wsum[BLK / 64];

  const int tid  = threadIdx.x;
  const int wid  = tid >> 6;          // wave 0..3
  const int lane = tid & 63;

  // ---- stage this block's 128 queries into LDS ----
  if (tid < QPB) {
    const int qi = qblk * QPB + tid;
    const float qx = q_base[qi * 3 + 0];
    const float qy = q_base[qi * 3 + 1];
    const float qz = q_base[qi * 3 + 2];
    qds[tid] = make_float4(-2.0f * qx, -2.0f * qy, -2.0f * qz,
                           qx * qx + qy * qy + qz * qz);
  }

  // ---- load 16 db points per lane into registers, f2-packed ----
  f2 px[PPL / 2], py[PPL / 2], pz[PPL / 2], pw[PPL / 2];
  {
    const int p0 = wid * PPW + lane * PPL;
#pragma unroll
    for (int j = 0; j < PPL / 2; ++j) {
      const int pa = p0 + 2 * j;
      const float ax = d_base[pa * 3 + 0];
      const float ay = d_base[pa * 3 + 1];
      const float az = d_base[pa * 3 + 2];
      const float bx = d_base[pa * 3 + 3];
      const float by = d_base[pa * 3 + 4];
      const float bz = d_base[pa * 3 + 5];
      px[j] = (f2){ax, bx};
      py[j] = (f2){ay, by};
      pz[j] = (f2){az, bz};
      pw[j] = (f2){ax * ax + ay * ay + az * az,
                   bx * bx + by * by + bz * bz};
    }
  }
  __syncthreads();

  // ---- stream queries: one query per wave-step, all 64 lanes contribute ----
#pragma unroll 2
  for (int s = 0; s < QPB; ++s) {
    const float4 qv = qds[s];           // wave-uniform -> LDS broadcast
    const f2 qxx = {qv.x, qv.x}, qyy = {qv.y, qv.y}, qzz = {qv.z, qv.z};
    float ml;
#pragma unroll
    for (int j = 0; j < PPL / 2; ++j) {
      const f2 v = __builtin_elementwise_fma(px[j], qxx,
                   __builtin_elementwise_fma(py[j], qyy,
                   __builtin_elementwise_fma(pz[j], qzz, pw[j])));
      if (j == 0) ml = fminf(v.x, v.y);
      else        ml = fminf(fminf(v.x, v.y), ml);   // -> v_min3_f32
    }
    // full-wave min reduction (all 64 lanes hold distinct db points)
    ml = fminf(ml, __shfl_xor(ml, 1));
    ml = fminf(ml, __shfl_xor(ml, 2));
    ml = fminf(ml, __shfl_xor(ml, 4));
    ml = fminf(ml, __shfl_xor(ml, 8));
    ml = fminf(ml, __shfl_xor(ml, 16));
    ml = fminf(ml, __shfl_xor(ml, 32));
    if (lane == 0) qpart[s * 4 + wid] = ml;
  }
  __syncthreads();

  // ---- combine 4 wave-partials per query, sqrt, mean ----
  float local = 0.0f;
  if (tid < QPB) {
    const float mm = fminf(fminf(qpart[tid * 4 + 0], qpart[tid * 4 + 1]),
                           fminf(qpart[tid * 4 + 2], qpart[tid * 4 + 3]));
    local = sqrtf(fmaxf(qds[tid].w + mm, 0.0f) + 1e-6f)
          * (1.0f / (float)(NB * NP));
  }
#pragma unroll
  for (int off = 32; off > 0; off >>= 1)
    local += __shfl_down(local, off);
  if (lane == 0) wsum[wid] = local;
  __syncthreads();
  if (tid == 0) {
    float s = 0.0f;
#pragma unroll
    for (int w = 0; w < BLK / 64; ++w) s += wsum[w];
    atomicAdd(out, s);
  }
}

extern "C" void kernel_launch(void* const* d_in, const int* in_sizes, int n_in,
                              void* d_out, int out_size, void* d_ws, size_t ws_size,
                              hipStream_t stream) {
  const float* x = (const float*)d_in[0];
  const float* y = (const float*)d_in[1];
  float* out = (float*)d_out;

  chamfer_init<<<1, 64, 0, stream>>>(out);
  chamfer_main<<<NBLOCKS, BLK, 0, stream>>>(x, y, out);
}

// Round 12
// 100.477 us; speedup vs baseline: 1.2450x; 1.2450x over previous
//
#include <hip/hip_runtime.h>

// ChamferLoss: x,y (16,4096,3) f32 -> scalar.
// R12: occupancy experiment on the R7/R8 structure. VOP3 (v_fma/v_min3,
// 3 VGPR reads) issues at ~1/3cyc (m07: 103TF == the 1/3-cyc ceiling), so
// the true floor is ~36us, and R8's 48us at 2 waves/SIMD is latency holes.
// BLK 256->512 with RQ 8->4 gives 512 blocks x 8 waves = 4096 waves =
// 4/SIMD (2 blocks/CU x 64KB LDS = 128/160KB). LDS reads per FLOP double
// vs R8 but are 8-way-broadcast b128 (~128B bank traffic each) - cheap.
// Inner loop unchanged: 3 fma + 0.5 min3 per pair, db split inside wave
// (td=lane&7), per-query min closed by 3 shfl_xor, one atomicAdd/block.

#define NP 4096
#define NB 16
#define BLK 512
#define NZZ (2 * NB)            // 32 (dir,b)
#define RQ 4                    // queries per lane
#define NWAVES (BLK / 64)       // 8
#define QPW 32                  // queries per wave (8 tq * RQ)
#define QPB (NWAVES * QPW)      // 256 queries per block
#define BPZ (NP / QPB)          // 16 blocks per zz
#define NBLOCKS (NZZ * BPZ)     // 512

__global__ void chamfer_init(float* __restrict__ out) { out[0] = 0.0f; }

__global__ __launch_bounds__(BLK, 4) void chamfer_main(
    const float* __restrict__ x, const float* __restrict__ y,
    float* __restrict__ out) {
  const int bid  = blockIdx.x;
  const int zz   = bid >> 4;          // /BPZ
  const int qblk = bid & (BPZ - 1);
  const int dir  = zz >> 4;
  const int b    = zz & 15;

  const float* q_base = (dir == 0 ? x : y) + (size_t)b * NP * 3;
  const float* d_base = (dir == 0 ? y : x) + (size_t)b * NP * 3;

  // ---- stage full db (4096 pts) into LDS as (x,y,z,d2) ----
  __shared__ float4 dpt[NP];          // 64 KB
  for (int p = threadIdx.x; p < NP; p += BLK) {
    const float dx = d_base[p * 3 + 0];
    const float dy = d_base[p * 3 + 1];
    const float dz = d_base[p * 3 + 2];
    dpt[p] = make_float4(dx, dy, dz, dx * dx + dy * dy + dz * dz);
  }
  __syncthreads();

  const int wid  = threadIdx.x >> 6;  // wave 0..7
  const int lane = threadIdx.x & 63;
  const int td   = lane & 7;          // db slice 0..7
  const int tq   = lane >> 3;         // query group 0..7

  // this lane's RQ queries
  float qpx[RQ], qpy[RQ], qpz[RQ], q2[RQ], m[RQ];
#pragma unroll
  for (int r = 0; r < RQ; ++r) {
    const int qi = qblk * QPB + wid * QPW + tq * RQ + r;
    const float qx = q_base[qi * 3 + 0];
    const float qy = q_base[qi * 3 + 1];
    const float qz = q_base[qi * 3 + 2];
    q2[r]  = qx * qx + qy * qy + qz * qz;
    qpx[r] = -2.0f * qx;
    qpy[r] = -2.0f * qy;
    qpz[r] = -2.0f * qz;
    m[r]   = 3.4e38f;
  }

  // ---- min over this lane's db slice: points t*8+td, t in [0,512) ----
#pragma unroll 4
  for (int t = 0; t < NP / 8; t += 2) {
    const float4 d0 = dpt[t * 8 + td];
    const float4 d1 = dpt[(t + 1) * 8 + td];
#pragma unroll
    for (int r = 0; r < RQ; ++r) {
      const float v0 = fmaf(d0.x, qpx[r], fmaf(d0.y, qpy[r], fmaf(d0.z, qpz[r], d0.w)));
      const float v1 = fmaf(d1.x, qpx[r], fmaf(d1.y, qpy[r], fmaf(d1.z, qpz[r], d1.w)));
      m[r] = fminf(fminf(v0, v1), m[r]);   // -> v_min3_f32
    }
  }

  // ---- reduce mins across the 8 td lanes of each octet ----
#pragma unroll
  for (int r = 0; r < RQ; ++r) {
    m[r] = fminf(m[r], __shfl_xor(m[r], 1));
    m[r] = fminf(m[r], __shfl_xor(m[r], 2));
    m[r] = fminf(m[r], __shfl_xor(m[r], 4));
  }

  // ---- epilogue: sqrt + partial mean (td==0 lanes only) ----
  float local = 0.0f;
  if (td == 0) {
#pragma unroll
    for (int r = 0; r < RQ; ++r)
      local += sqrtf(fmaxf(q2[r] + m[r], 0.0f) + 1e-6f);
    local *= (1.0f / (float)(NB * NP));
  }

  // wave reduce (octet leaders), then block reduce, one atomic per block
#pragma unroll
  for (int off = 32; off > 0; off >>= 1)
    local += __shfl_down(local, off);

  __shared__ float wsum[NWAVES];
  if (lane == 0) wsum[wid] = local;
  __syncthreads();
  if (threadIdx.x == 0) {
    float s = 0.0f;
#pragma unroll
    for (int w = 0; w < NWAVES; ++w) s += wsum[w];
    atomicAdd(out, s);
  }
}

extern "C" void kernel_launch(void* const* d_in, const int* in_sizes, int n_in,
                              void* d_out, int out_size, void* d_ws, size_t ws_size,
                              hipStream_t stream) {
  const float* x = (const float*)d_in[0];
  const float* y = (const float*)d_in[1];
  float* out = (float*)d_out;

  chamfer_init<<<1, 64, 0, stream>>>(out);
  chamfer_main<<<NBLOCKS, BLK, 0, stream>>>(x, y, out);
}